// Round 14
// baseline (238.203 us; speedup 1.0000x reference)
//
#include <hip/hip_runtime.h>
#include <math.h>

#define N_NODES 8192
#define N_EDGES 262144
#define INV_SQRT3 0.5773502691896258f

typedef __attribute__((ext_vector_type(8))) _Float16 half8;
typedef __attribute__((ext_vector_type(4))) _Float16 half4v;
typedef __attribute__((ext_vector_type(4))) float floatx4;

#define MF16(a,b,c)  __builtin_amdgcn_mfma_f32_16x16x32_f16(a,b,c,0,0,0)
// legacy shape builtin: no underscore before f16 (compiler-suggested name)
#define MF16A(a,b,c) __builtin_amdgcn_mfma_f32_16x16x16f16(a,b,c,0,0,0)

__device__ __forceinline__ float sspf(float x){
    // softplus(x)-ln2 = ln2*(log2(1+2^(x*log2e)) - 1); exp2f/log2f lower to
    // native v_exp_f32/v_log_f32 (base-2 hw ops) on gfx950
    return (x > 20.0f) ? (x - 0.69314718f)
         : 0.69314718f * (log2f(1.0f + exp2f(x * 1.44269504f)) - 1.0f);
}

// ---------------------------------------------------------------------------
// Node kernel (R6/R9 version, verbatim): factored sc einsum, q/qd PERMUTED
// into qdbuf[n][col*8+slot], feats16 DE-INTERLEAVED [x0|xa|xb|xc], CSR degree
// histogram folded in.
// ---------------------------------------------------------------------------
__global__ __launch_bounds__(256) void node_kernel(
    const float* __restrict__ feats, const float* __restrict__ attrs,
    const float* __restrict__ Wq0, const float* __restrict__ Wq1,
    const float* __restrict__ Wd0, const float* __restrict__ Wd1,
    const float* __restrict__ Ws0, const float* __restrict__ Ws1,
    float* __restrict__ qdbuf, float* __restrict__ out,
    _Float16* __restrict__ feats16,
    const int* __restrict__ eidx, int* __restrict__ degb)
{
    __shared__ float sa[4][16];
    __shared__ float sT[4][4][32];
    __shared__ float Tl[2][4][1152];   // T, rows stride 36
    __shared__ float qT[4][4][32];
    __shared__ float qsh[4][128];

    const int t  = threadIdx.x;
    const int nb = blockIdx.x * 4;

    const float inv_sqrt32 = 0.17677669529663687f;
    const float sc_scale   = 0.04419417382415922f;
    const float d_scale    = 0.022097086912079608f;

    // folded count_kernel: 2048 blocks x 128 edges = 262144
    if (t < 128){
        int e = blockIdx.x*128 + t;
        atomicAdd(&degb[eidx[N_EDGES + e]], 1);
    }

    for (int i = t; i < 512; i += 256){
        int nn = i >> 7, r = i & 127;
        int p = r >> 5, u = r & 31;
        int off = (p==0) ? u : 32 + u*3 + (p-1);
        float val = feats[(size_t)(nb+nn)*128 + off];
        sT[nn][p][u] = val;
        // de-interleaved fp16 layout: x0 at [0,32), xa at [32,64), xb, xc
        int off16 = (p==0) ? u : p*32 + u;
        feats16[(size_t)(nb+nn)*128 + off16] = (_Float16)val;
    }
    if (t < 64) sa[t>>4][t&15] = attrs[(size_t)(nb + (t>>4))*16 + (t&15)];
    __syncthreads();

    const int v  = t & 31;
    const int g5 = (t >> 5) & 3;
    const int hi = t >> 7;

    {
        const float* __restrict__ Wm = hi ? Ws1 : Ws0;
        float sar[4][16];
        #pragma unroll
        for (int nn = 0; nn < 4; ++nn)
            #pragma unroll
            for (int a = 0; a < 16; ++a) sar[nn][a] = sa[nn][a];
        #pragma unroll
        for (int uu = 0; uu < 8; ++uu){
            int u = g5*8 + uu;
            float a0=0.f, a1=0.f, a2=0.f, a3=0.f;
            #pragma unroll
            for (int a = 0; a < 16; ++a){
                float w = Wm[(u*16 + a)*32 + v];
                a0 += sar[0][a]*w; a1 += sar[1][a]*w;
                a2 += sar[2][a]*w; a3 += sar[3][a]*w;
            }
            Tl[hi][0][v*36+u] = a0; Tl[hi][1][v*36+u] = a1;
            Tl[hi][2][v*36+u] = a2; Tl[hi][3][v*36+u] = a3;
        }
    }
    __syncthreads();

    const int p  = g5;
    const int n0 = hi*2, n1 = n0 + 1;
    const int mm = (p==0) ? 0 : 1;
    const float* __restrict__ Wqp = (p==0) ? Wq0 : Wq1;
    const float* __restrict__ Wdp = (p==0) ? Wd0 : Wd1;
    const int oidx = (p==0) ? v : 32 + v*3 + (p-1);

    float c0=0.f, c1=0.f;
    #pragma unroll
    for (int uc = 0; uc < 8; ++uc){
        float4 t0 = *(const float4*)&Tl[mm][n0][v*36 + uc*4];
        float4 t1 = *(const float4*)&Tl[mm][n1][v*36 + uc*4];
        float4 s0 = *(const float4*)&sT[n0][p][uc*4];
        float4 s1 = *(const float4*)&sT[n1][p][uc*4];
        c0 += t0.x*s0.x + t0.y*s0.y + t0.z*s0.z + t0.w*s0.w;
        c1 += t1.x*s1.x + t1.y*s1.y + t1.z*s1.z + t1.w*s1.w;
    }
    out[(size_t)(nb+n0)*128 + oidx] = c0 * sc_scale;
    out[(size_t)(nb+n1)*128 + oidx] = c1 * sc_scale;

    float q0=0.f, q1=0.f;
    #pragma unroll
    for (int u = 0; u < 32; ++u){
        float w = Wqp[u*32 + v];
        q0 += sT[n0][p][u] * w;
        q1 += sT[n1][p][u] * w;
    }
    qT[n0][p][v] = q0 * inv_sqrt32;
    qT[n1][p][v] = q1 * inv_sqrt32;
    __syncthreads();

    float d0=0.f, d1=0.f;
    #pragma unroll
    for (int u = 0; u < 32; ++u){
        float w = Wdp[u*32 + v];
        d0 += qT[n0][p][u] * w;
        d1 += qT[n1][p][u] * w;
    }
    float dsc = (p==0) ? d_scale : d_scale * INV_SQRT3;
    qsh[n0][oidx] = d0 * dsc;
    qsh[n1][oidx] = d1 * dsc;
    __syncthreads();

    for (int i = t; i < 512; i += 256){
        int nn = i >> 7, tt = i & 127;
        int col = tt >> 3, slot = tt & 7;
        int src;
        if      (slot == 0) src = col;
        else if (slot == 1) src = col + 16;
        else if (slot <  5) src = 32 + 3*col + (slot-2);
        else                src = 32 + 3*(col+16) + (slot-5);
        qdbuf[(size_t)(nb+nn)*128 + tt] = qsh[nn][src];
    }
}

// ---------------------------------------------------------------------------
// CSR build: exclusive scan -> scatter+REORDER into 48-B records.
// ---------------------------------------------------------------------------
__global__ __launch_bounds__(256) void scan_kernel(
    const int* __restrict__ degb, int* __restrict__ rowstart,
    int* __restrict__ cursor)
{
    __shared__ int part[256];
    int t = threadIdx.x;
    int loc[32];
    int s = 0;
    #pragma unroll
    for (int i = 0; i < 32; ++i){ loc[i] = s; s += degb[t*32 + i]; }
    part[t] = s;
    __syncthreads();
    for (int d = 1; d < 256; d <<= 1){
        int v = (t >= d) ? part[t-d] : 0;
        __syncthreads();
        part[t] += v;
        __syncthreads();
    }
    int excl = part[t] - s;
    #pragma unroll
    for (int i = 0; i < 32; ++i){
        int v = excl + loc[i];
        rowstart[t*32 + i] = v;
        cursor[t*32 + i]   = v;
    }
    if (t == 255) rowstart[N_NODES] = excl + s;
}

// 48-B record per edge: [emb16 32B][eattr fp16x4 8B][src 4B][pad 4B].
__global__ __launch_bounds__(256) void scatter_kernel(
    const int* __restrict__ eidx, const float* __restrict__ emb,
    const float* __restrict__ eattr, int* __restrict__ cursor,
    char* __restrict__ recbuf)
{
    int e = blockIdx.x*256 + threadIdx.x;
    int dst = eidx[N_EDGES + e];
    int src = eidx[e];
    float4 a4 = *(const float4*)(eattr + (size_t)e*4);
    const float4* ep = (const float4*)(emb + (size_t)e*16);
    float4 v0 = ep[0], v1 = ep[1], v2 = ep[2], v3 = ep[3];
    half8 h0, h1;
    h0[0]=(_Float16)v0.x; h0[1]=(_Float16)v0.y; h0[2]=(_Float16)v0.z; h0[3]=(_Float16)v0.w;
    h0[4]=(_Float16)v1.x; h0[5]=(_Float16)v1.y; h0[6]=(_Float16)v1.z; h0[7]=(_Float16)v1.w;
    h1[0]=(_Float16)v2.x; h1[1]=(_Float16)v2.y; h1[2]=(_Float16)v2.z; h1[3]=(_Float16)v2.w;
    h1[4]=(_Float16)v3.x; h1[5]=(_Float16)v3.y; h1[6]=(_Float16)v3.z; h1[7]=(_Float16)v3.w;
    half4v y4;
    y4[0]=(_Float16)a4.x; y4[1]=(_Float16)a4.y; y4[2]=(_Float16)a4.z; y4[3]=(_Float16)a4.w;
    int2 yb = *(int2*)&y4;
    int4 tail; tail.x = yb.x; tail.y = yb.y; tail.z = src; tail.w = 0;
    int p = atomicAdd(&cursor[dst], 1);
    char* wp = recbuf + (size_t)p*48;
    *(half8*)(wp)      = h0;
    *(half8*)(wp + 16) = h1;
    *(int4*)(wp + 32)  = tail;
}

// ---------------------------------------------------------------------------
// FUSED edge pass — R13 (= R12 with portable exp2f/log2f): 8 nodes/block
// (2 nodes per warp, sequential) to amortize the prologue (weight loads +
// fragment building) 2x. Grid 1024; warp g handles nodes blk*8+g, blk*8+4+g.
// LDS = 4096 + 32768 + 17408 = 54272. 16x16x16 layouts (std CDNA 4-elem
// k-groups): A[m=lane&15][k=quad*4+j]; B[k=quad*4+j][n=lane&15]; C unchanged.
// 16x16x32 layouts (measured m89/m120) unchanged for GEMM2/lin.
// ---------------------------------------------------------------------------

#define G1STAGE(FRAG, OFF) { \
    floatx4 hh = MF16A(ea, FRAG, zzero); \
    stag[g][quad*4+0][(OFF)+col] = (_Float16)sspf(hh[0]); \
    stag[g][quad*4+1][(OFF)+col] = (_Float16)sspf(hh[1]); \
    stag[g][quad*4+2][(OFF)+col] = (_Float16)sspf(hh[2]); \
    stag[g][quad*4+3][(OFF)+col] = (_Float16)sspf(hh[3]); }

#define G2STAGE(A0, A1, B0, B1, OFF) { \
    floatx4 wcx = MF16(A0, B0, zzero); wcx = MF16(A1, B1, wcx); \
    stag[g][quad*4+0][(OFF)+col] = (_Float16)wcx[0]; \
    stag[g][quad*4+1][(OFF)+col] = (_Float16)wcx[1]; \
    stag[g][quad*4+2][(OFF)+col] = (_Float16)wcx[2]; \
    stag[g][quad*4+3][(OFF)+col] = (_Float16)wcx[3]; }

__global__ __launch_bounds__(256, 2) void edge_fused(
    const _Float16* __restrict__ feats16, const char* __restrict__ recbuf,
    const float* __restrict__ Wk1,  const float* __restrict__ Wk2,
    const float* __restrict__ Wlk0, const float* __restrict__ Wlk1,
    const float* __restrict__ Wv1,  const float* __restrict__ Wv2,
    const float* __restrict__ Wlv0, const float* __restrict__ Wlv1,
    const float* __restrict__ qdbuf,
    const int* __restrict__ rowstart,
    float* __restrict__ out)
{
    __shared__ half4v fW1[2][4][64];       // K=16 fragments (4 KB)
    __shared__ half8  fW2[2][16][64];      // 32 KB
    __shared__ _Float16 stag[4][16][136];  // 17.4 KB

    const int t    = threadIdx.x;
    const int lane = t & 63;
    const int col  = lane & 15;
    const int quad = lane >> 4;
    const int g    = t >> 6;          // warp id 0..3

    // ---- lin B-fragments in REGISTERS (per-lane constants, all warps) ----
    half8 rL0k[4], rL1k[4], rL0v[4], rL1v[4];
    #pragma unroll
    for (int ff = 0; ff < 4; ++ff){
        int tile = ff >> 1, s = ff & 1;
        #pragma unroll
        for (int j = 0; j < 8; ++j){
            int k = (s*32 + quad*8 + j)*32 + tile*16 + col;
            rL0k[ff][j] = (_Float16)(Wlk0[k] * 0.125f);
            rL1k[ff][j] = (_Float16)(Wlk1[k] * 0.125f);
            rL0v[ff][j] = (_Float16)(Wlv0[k] * 0.125f);
            rL1v[ff][j] = (_Float16)(Wlv1[k] * 0.125f);
        }
    }

    // ---- preload GEMM1 (K16) + GEMM2 weight fragments (scales folded) ----
    #pragma unroll
    for (int kv = 0; kv < 2; ++kv){
        const float* __restrict__ W1 = kv ? Wv1  : Wk1;
        const float* __restrict__ W2 = kv ? Wv2  : Wk2;
        {
            half4v f;
            #pragma unroll
            for (int j = 0; j < 4; ++j)
                f[j] = (_Float16)(W1[(quad*4 + j)*64 + g*16 + col] * 0.25f);
            fW1[kv][g][lane] = f;
        }
        #pragma unroll
        for (int ff = 0; ff < 4; ++ff){
            int fr = g*4 + ff, tile = fr >> 1, s = fr & 1;
            // fr>=12 produce w3 (cols 96..127): fold INV_SQRT3 here
            float w2sc = (fr >= 12) ? (0.125f * INV_SQRT3) : 0.125f;
            half8 f;
            #pragma unroll
            for (int j = 0; j < 8; ++j)
                f[j] = (_Float16)(W2[(s*32 + quad*8 + j)*128 + tile*16 + col] * w2sc);
            fW2[kv][fr][lane] = f;
        }
    }
    __syncthreads();     // the only block-wide barrier

    const floatx4 zzero = {0.f, 0.f, 0.f, 0.f};

    // ---- two nodes per warp, sequential ----
    for (int sub = 0; sub < 2; ++sub){
        const int n  = blockIdx.x*8 + sub*4 + g;
        const int r0 = rowstart[n];
        const int dcount = rowstart[n+1] - r0;

        const float* qdp = qdbuf + (size_t)n*128 + col*8;
        float4 qa = *(const float4*)qdp;
        float4 qb = *(const float4*)(qdp + 4);

        float macc0=0.f, macc1=0.f, macc2=0.f, macc3=0.f;
        float macc4=0.f, macc5=0.f, macc6=0.f, macc7=0.f;
        float zacc = 0.f;

        for (int tb = 0; tb < dcount; tb += 16){
            int slot = tb + col;
            int pc = r0 + ((slot < dcount) ? slot : (dcount-1));

            // ---- per-edge 48-B record (CSR-sequential across lanes) ----
            const char* rp = recbuf + (size_t)pc*48;
            half4v ea = *(const half4v*)(rp + quad*8);   // A[m][k=quad*4+j]
            half4v yh = *(const half4v*)(rp + 32);
            const int srcm = *(const int*)(rp + 40);
            const _Float16* fsrc = feats16 + (size_t)srcm*128;

            // de-interleaved x planes: direct half8 loads
            half8 hx  = *(const half8*)(fsrc + quad*8);
            half8 hxa = *(const half8*)(fsrc + 32 + quad*8);
            half8 hxb = *(const half8*)(fsrc + 64 + quad*8);
            half8 hxc = *(const half8*)(fsrc + 96 + quad*8);

            // ---- shared x*y products, PACKED fp16 (used by BOTH k and v) --
            _Float16 hy0  = yh[0];
            _Float16 hy1a = yh[1];
            _Float16 hy1b = yh[2];
            _Float16 hy1c = yh[3];
            half8 y0v  = {hy0,hy0,hy0,hy0,hy0,hy0,hy0,hy0};
            half8 y1av = {hy1a,hy1a,hy1a,hy1a,hy1a,hy1a,hy1a,hy1a};
            half8 y1bv = {hy1b,hy1b,hy1b,hy1b,hy1b,hy1b,hy1b,hy1b};
            half8 y1cv = {hy1c,hy1c,hy1c,hy1c,hy1c,hy1c,hy1c,hy1c};
            half8 px00 = hx  * y0v;
            half8 pxa  = hx  * y1av;
            half8 pxb  = hx  * y1bv;
            half8 pxc  = hx  * y1cv;
            half8 pay  = hxa * y0v;
            half8 pby  = hxb * y0v;
            half8 pcy  = hxc * y0v;
            half8 pdot = hxa*y1av + hxb*y1bv + hxc*y1cv; // *INV_SQRT3 in fW2

            // ---- GEMM1 (k AND v, shared A, K=16) -> ssp -> staged ----
            G1STAGE(fW1[0][0][lane],   0)
            G1STAGE(fW1[0][1][lane],  16)
            G1STAGE(fW1[0][2][lane],  32)
            G1STAGE(fW1[0][3][lane],  48)
            G1STAGE(fW1[1][0][lane],  64)
            G1STAGE(fW1[1][1][lane],  80)
            G1STAGE(fW1[1][2][lane],  96)
            G1STAGE(fW1[1][3][lane], 112)

            half8 a0k = *(const half8*)&stag[g][col][     quad*8];
            half8 a1k = *(const half8*)&stag[g][col][32 + quad*8];
            half8 a0v = *(const half8*)&stag[g][col][64 + quad*8];
            half8 a1v = *(const half8*)&stag[g][col][96 + quad*8];

            // ---- GEMM2 k (overlay; same-wave DS in-order) ----
            G2STAGE(a0k, a1k, fW2[0][ 0][lane], fW2[0][ 1][lane],   0)
            G2STAGE(a0k, a1k, fW2[0][ 2][lane], fW2[0][ 3][lane],  16)
            G2STAGE(a0k, a1k, fW2[0][ 4][lane], fW2[0][ 5][lane],  32)
            G2STAGE(a0k, a1k, fW2[0][ 6][lane], fW2[0][ 7][lane],  48)
            G2STAGE(a0k, a1k, fW2[0][ 8][lane], fW2[0][ 9][lane],  64)
            G2STAGE(a0k, a1k, fW2[0][10][lane], fW2[0][11][lane],  80)
            G2STAGE(a0k, a1k, fW2[0][12][lane], fW2[0][13][lane],  96)
            G2STAGE(a0k, a1k, fW2[0][14][lane], fW2[0][15][lane], 112)

            half8 w0hk = *(const half8*)&stag[g][col][     quad*8];
            half8 w1hk = *(const half8*)&stag[g][col][32 + quad*8];
            half8 w2hk = *(const half8*)&stag[g][col][64 + quad*8];
            half8 w3hk = *(const half8*)&stag[g][col][96 + quad*8];

            // ---- GEMM2 v (k-reads above precede overlay writes) ----
            G2STAGE(a0v, a1v, fW2[1][ 0][lane], fW2[1][ 1][lane],   0)
            G2STAGE(a0v, a1v, fW2[1][ 2][lane], fW2[1][ 3][lane],  16)
            G2STAGE(a0v, a1v, fW2[1][ 4][lane], fW2[1][ 5][lane],  32)
            G2STAGE(a0v, a1v, fW2[1][ 6][lane], fW2[1][ 7][lane],  48)
            G2STAGE(a0v, a1v, fW2[1][ 8][lane], fW2[1][ 9][lane],  64)
            G2STAGE(a0v, a1v, fW2[1][10][lane], fW2[1][11][lane],  80)
            G2STAGE(a0v, a1v, fW2[1][12][lane], fW2[1][13][lane],  96)
            G2STAGE(a0v, a1v, fW2[1][14][lane], fW2[1][15][lane], 112)

            // ---- uvu k fragments: ONE packed mul each ----
            half8 fk0s0 = w0hk * px00;
            half8 fk0s1 = w3hk * pdot;
            half8 fc0s0 = w1hk * pxa;
            half8 fc1s0 = w1hk * pxb;
            half8 fc2s0 = w1hk * pxc;
            half8 fc0s1 = w2hk * pay;
            half8 fc1s1 = w2hk * pby;
            half8 fc2s1 = w2hk * pcy;

            // ---- lin k folded into ddv as produced (B from registers) ----
            floatx4 ddv = zzero;
            {
                floatx4 tk;
                tk = MF16(fk0s0, rL0k[0], zzero); tk = MF16(fk0s1, rL0k[1], tk);
                ddv += tk * qa.x;
                tk = MF16(fk0s0, rL0k[2], zzero); tk = MF16(fk0s1, rL0k[3], tk);
                ddv += tk * qa.y;
                tk = MF16(fc0s0, rL1k[0], zzero); tk = MF16(fc0s1, rL1k[1], tk);
                ddv += tk * qa.z;
                tk = MF16(fc1s0, rL1k[0], zzero); tk = MF16(fc1s1, rL1k[1], tk);
                ddv += tk * qa.w;
                tk = MF16(fc2s0, rL1k[0], zzero); tk = MF16(fc2s1, rL1k[1], tk);
                ddv += tk * qb.x;
                tk = MF16(fc0s0, rL1k[2], zzero); tk = MF16(fc0s1, rL1k[3], tk);
                ddv += tk * qb.y;
                tk = MF16(fc1s0, rL1k[2], zzero); tk = MF16(fc1s1, rL1k[3], tk);
                ddv += tk * qb.z;
                tk = MF16(fc2s0, rL1k[2], zzero); tk = MF16(fc2s1, rL1k[3], tk);
                ddv += tk * qb.w;
            }

            float cf0, cf1, cf2, cf3;
            #pragma unroll
            for (int r = 0; r < 4; ++r){
                float dd = ddv[r];
                dd += __shfl_xor(dd, 1);
                dd += __shfl_xor(dd, 2);
                dd += __shfl_xor(dd, 4);
                dd += __shfl_xor(dd, 8);
                // cutoff const: diff = pos[src]-pos[src] == 0 (reference bug)
                bool valid = (tb + quad*4 + r) < dcount;
                float ev = valid ? (0.9048374180359595f * __expf(dd)) : 0.f;
                zacc += ev;
                float cf = sqrtf(ev);
                if (r==0) cf0 = cf; else if (r==1) cf1 = cf;
                else if (r==2) cf2 = cf; else cf3 = cf;
            }

            // ---- read back w_v, packed v fragments (reuse registers) ----
            {
                half8 w0hv = *(const half8*)&stag[g][col][     quad*8];
                half8 w1hv = *(const half8*)&stag[g][col][32 + quad*8];
                half8 w2hv = *(const half8*)&stag[g][col][64 + quad*8];
                half8 w3hv = *(const half8*)&stag[g][col][96 + quad*8];
                fk0s0 = w0hv * px00;
                fk0s1 = w3hv * pdot;
                fc0s0 = w1hv * pxa;
                fc1s0 = w1hv * pxb;
                fc2s0 = w1hv * pxc;
                fc0s1 = w2hv * pay;
                fc1s1 = w2hv * pby;
                fc2s1 = w2hv * pcy;
            }

            // ---- lin v folded into macc scalars (B from registers) ----
            {
                floatx4 tv;
                tv = MF16(fk0s0, rL0v[0], zzero); tv = MF16(fk0s1, rL0v[1], tv);
                macc0 += cf0*tv[0] + cf1*tv[1] + cf2*tv[2] + cf3*tv[3];
                tv = MF16(fk0s0, rL0v[2], zzero); tv = MF16(fk0s1, rL0v[3], tv);
                macc1 += cf0*tv[0] + cf1*tv[1] + cf2*tv[2] + cf3*tv[3];
                tv = MF16(fc0s0, rL1v[0], zzero); tv = MF16(fc0s1, rL1v[1], tv);
                macc2 += cf0*tv[0] + cf1*tv[1] + cf2*tv[2] + cf3*tv[3];
                tv = MF16(fc1s0, rL1v[0], zzero); tv = MF16(fc1s1, rL1v[1], tv);
                macc3 += cf0*tv[0] + cf1*tv[1] + cf2*tv[2] + cf3*tv[3];
                tv = MF16(fc2s0, rL1v[0], zzero); tv = MF16(fc2s1, rL1v[1], tv);
                macc4 += cf0*tv[0] + cf1*tv[1] + cf2*tv[2] + cf3*tv[3];
                tv = MF16(fc0s0, rL1v[2], zzero); tv = MF16(fc0s1, rL1v[3], tv);
                macc5 += cf0*tv[0] + cf1*tv[1] + cf2*tv[2] + cf3*tv[3];
                tv = MF16(fc1s0, rL1v[2], zzero); tv = MF16(fc1s1, rL1v[3], tv);
                macc6 += cf0*tv[0] + cf1*tv[1] + cf2*tv[2] + cf3*tv[3];
                tv = MF16(fc2s0, rL1v[2], zzero); tv = MF16(fc2s1, rL1v[3], tv);
                macc7 += cf0*tv[0] + cf1*tv[1] + cf2*tv[2] + cf3*tv[3];
            }
        }

        // ---- reduce over quads; rsqrt(z) factored scaling; write out ----
        macc0 += __shfl_xor(macc0, 16); macc0 += __shfl_xor(macc0, 32);
        macc1 += __shfl_xor(macc1, 16); macc1 += __shfl_xor(macc1, 32);
        macc2 += __shfl_xor(macc2, 16); macc2 += __shfl_xor(macc2, 32);
        macc3 += __shfl_xor(macc3, 16); macc3 += __shfl_xor(macc3, 32);
        macc4 += __shfl_xor(macc4, 16); macc4 += __shfl_xor(macc4, 32);
        macc5 += __shfl_xor(macc5, 16); macc5 += __shfl_xor(macc5, 32);
        macc6 += __shfl_xor(macc6, 16); macc6 += __shfl_xor(macc6, 32);
        macc7 += __shfl_xor(macc7, 16); macc7 += __shfl_xor(macc7, 32);
        zacc  += __shfl_xor(zacc, 16);  zacc  += __shfl_xor(zacc, 32);
        float rz = (zacc > 0.f) ? rsqrtf(zacc) : 0.f;

        if (lane < 16){
            float* op = out + (size_t)n*128;
            op[col]                 += macc0 * rz;
            op[col + 16]            += macc1 * rz;
            op[32 + 3*col + 0]      += macc2 * rz;
            op[32 + 3*col + 1]      += macc3 * rz;
            op[32 + 3*col + 2]      += macc4 * rz;
            op[32 + 3*(col+16) + 0] += macc5 * rz;
            op[32 + 3*(col+16) + 1] += macc6 * rz;
            op[32 + 3*(col+16) + 2] += macc7 * rz;
        }
    }
}

extern "C" void kernel_launch(void* const* d_in, const int* in_sizes, int n_in,
                              void* d_out, int out_size, void* d_ws, size_t ws_size,
                              hipStream_t stream)
{
    const float* feats = (const float*)d_in[0];
    const float* attrs = (const float*)d_in[1];
    const float* emb   = (const float*)d_in[2];
    const float* eattr = (const float*)d_in[3];
    // d_in[4] positions: unused (reference computes positions[src]-positions[src] == 0)
    const float* Wq0  = (const float*)d_in[5];
    const float* Wq1  = (const float*)d_in[6];
    const float* Wk1  = (const float*)d_in[7];
    const float* Wk2  = (const float*)d_in[8];
    const float* Wv1  = (const float*)d_in[9];
    const float* Wv2  = (const float*)d_in[10];
    const float* Wlk0 = (const float*)d_in[11];
    const float* Wlk1 = (const float*)d_in[12];
    const float* Wlv0 = (const float*)d_in[13];
    const float* Wlv1 = (const float*)d_in[14];
    const float* Wd0  = (const float*)d_in[15];
    const float* Wd1  = (const float*)d_in[16];
    const float* Ws0  = (const float*)d_in[17];
    const float* Ws1  = (const float*)d_in[18];
    const int*   eidx = (const int*)d_in[19];

    float* out   = (float*)d_out;
    // workspace (18.97 MB total, < 20.02 MB proven-passing R1 footprint):
    char* recbuf = (char*)d_ws;                               // E*48 B = 12.58MB
    float* qdbuf = (float*)(recbuf + (size_t)N_EDGES*48);     // N*128 f = 4.19MB
    _Float16* feats16 = (_Float16*)(qdbuf + (size_t)N_NODES*128); // N*128 h = 2.1MB
    int*   degb  = (int*)(feats16 + (size_t)N_NODES*128);     // N
    int*   rowst = degb + N_NODES;                            // N+1
    int*   curs  = rowst + N_NODES + 1;                       // N

    hipMemsetAsync(degb, 0, N_NODES*sizeof(int), stream);
    node_kernel<<<N_NODES/4, 256, 0, stream>>>(feats, attrs, Wq0, Wq1, Wd0, Wd1,
                                               Ws0, Ws1, qdbuf, out, feats16,
                                               eidx, degb);
    scan_kernel<<<1, 256, 0, stream>>>(degb, rowst, curs);
    scatter_kernel<<<N_EDGES/256, 256, 0, stream>>>(eidx, emb, eattr, curs,
                                                    recbuf);
    edge_fused<<<N_NODES/8, 256, 0, stream>>>(feats16, recbuf,
                                              Wk1, Wk2, Wlk0, Wlk1,
                                              Wv1, Wv2, Wlv0, Wlv1,
                                              qdbuf, rowst, out);
}

// Round 15
// 234.825 us; speedup vs baseline: 1.0144x; 1.0144x over previous
//
#include <hip/hip_runtime.h>
#include <math.h>

#define N_NODES 8192
#define N_EDGES 262144
#define INV_SQRT3 0.5773502691896258f

typedef __attribute__((ext_vector_type(8))) _Float16 half8;
typedef __attribute__((ext_vector_type(4))) _Float16 half4v;
typedef __attribute__((ext_vector_type(4))) float floatx4;

#define MF16(a,b,c)  __builtin_amdgcn_mfma_f32_16x16x32_f16(a,b,c,0,0,0)
// legacy shape builtin: no underscore before f16 (compiler-suggested name)
#define MF16A(a,b,c) __builtin_amdgcn_mfma_f32_16x16x16f16(a,b,c,0,0,0)

__device__ __forceinline__ float sspf(float x){
    // softplus(x) - ln2 via hw v_exp/v_log
    return (x > 20.0f) ? (x - 0.69314718f)
                       : (__logf(1.0f + __expf(x)) - 0.69314718f);
}

// ---------------------------------------------------------------------------
// Node kernel (R6/R9 version, verbatim): factored sc einsum, q/qd PERMUTED
// into qdbuf[n][col*8+slot], feats16 DE-INTERLEAVED [x0|xa|xb|xc], CSR degree
// histogram folded in.
// ---------------------------------------------------------------------------
__global__ __launch_bounds__(256) void node_kernel(
    const float* __restrict__ feats, const float* __restrict__ attrs,
    const float* __restrict__ Wq0, const float* __restrict__ Wq1,
    const float* __restrict__ Wd0, const float* __restrict__ Wd1,
    const float* __restrict__ Ws0, const float* __restrict__ Ws1,
    float* __restrict__ qdbuf, float* __restrict__ out,
    _Float16* __restrict__ feats16,
    const int* __restrict__ eidx, int* __restrict__ degb)
{
    __shared__ float sa[4][16];
    __shared__ float sT[4][4][32];
    __shared__ float Tl[2][4][1152];   // T, rows stride 36
    __shared__ float qT[4][4][32];
    __shared__ float qsh[4][128];

    const int t  = threadIdx.x;
    const int nb = blockIdx.x * 4;

    const float inv_sqrt32 = 0.17677669529663687f;
    const float sc_scale   = 0.04419417382415922f;
    const float d_scale    = 0.022097086912079608f;

    // folded count_kernel: 2048 blocks x 128 edges = 262144
    if (t < 128){
        int e = blockIdx.x*128 + t;
        atomicAdd(&degb[eidx[N_EDGES + e]], 1);
    }

    for (int i = t; i < 512; i += 256){
        int nn = i >> 7, r = i & 127;
        int p = r >> 5, u = r & 31;
        int off = (p==0) ? u : 32 + u*3 + (p-1);
        float val = feats[(size_t)(nb+nn)*128 + off];
        sT[nn][p][u] = val;
        // de-interleaved fp16 layout: x0 at [0,32), xa at [32,64), xb, xc
        int off16 = (p==0) ? u : p*32 + u;
        feats16[(size_t)(nb+nn)*128 + off16] = (_Float16)val;
    }
    if (t < 64) sa[t>>4][t&15] = attrs[(size_t)(nb + (t>>4))*16 + (t&15)];
    __syncthreads();

    const int v  = t & 31;
    const int g5 = (t >> 5) & 3;
    const int hi = t >> 7;

    {
        const float* __restrict__ Wm = hi ? Ws1 : Ws0;
        float sar[4][16];
        #pragma unroll
        for (int nn = 0; nn < 4; ++nn)
            #pragma unroll
            for (int a = 0; a < 16; ++a) sar[nn][a] = sa[nn][a];
        #pragma unroll
        for (int uu = 0; uu < 8; ++uu){
            int u = g5*8 + uu;
            float a0=0.f, a1=0.f, a2=0.f, a3=0.f;
            #pragma unroll
            for (int a = 0; a < 16; ++a){
                float w = Wm[(u*16 + a)*32 + v];
                a0 += sar[0][a]*w; a1 += sar[1][a]*w;
                a2 += sar[2][a]*w; a3 += sar[3][a]*w;
            }
            Tl[hi][0][v*36+u] = a0; Tl[hi][1][v*36+u] = a1;
            Tl[hi][2][v*36+u] = a2; Tl[hi][3][v*36+u] = a3;
        }
    }
    __syncthreads();

    const int p  = g5;
    const int n0 = hi*2, n1 = n0 + 1;
    const int mm = (p==0) ? 0 : 1;
    const float* __restrict__ Wqp = (p==0) ? Wq0 : Wq1;
    const float* __restrict__ Wdp = (p==0) ? Wd0 : Wd1;
    const int oidx = (p==0) ? v : 32 + v*3 + (p-1);

    float c0=0.f, c1=0.f;
    #pragma unroll
    for (int uc = 0; uc < 8; ++uc){
        float4 t0 = *(const float4*)&Tl[mm][n0][v*36 + uc*4];
        float4 t1 = *(const float4*)&Tl[mm][n1][v*36 + uc*4];
        float4 s0 = *(const float4*)&sT[n0][p][uc*4];
        float4 s1 = *(const float4*)&sT[n1][p][uc*4];
        c0 += t0.x*s0.x + t0.y*s0.y + t0.z*s0.z + t0.w*s0.w;
        c1 += t1.x*s1.x + t1.y*s1.y + t1.z*s1.z + t1.w*s1.w;
    }
    out[(size_t)(nb+n0)*128 + oidx] = c0 * sc_scale;
    out[(size_t)(nb+n1)*128 + oidx] = c1 * sc_scale;

    float q0=0.f, q1=0.f;
    #pragma unroll
    for (int u = 0; u < 32; ++u){
        float w = Wqp[u*32 + v];
        q0 += sT[n0][p][u] * w;
        q1 += sT[n1][p][u] * w;
    }
    qT[n0][p][v] = q0 * inv_sqrt32;
    qT[n1][p][v] = q1 * inv_sqrt32;
    __syncthreads();

    float d0=0.f, d1=0.f;
    #pragma unroll
    for (int u = 0; u < 32; ++u){
        float w = Wdp[u*32 + v];
        d0 += qT[n0][p][u] * w;
        d1 += qT[n1][p][u] * w;
    }
    float dsc = (p==0) ? d_scale : d_scale * INV_SQRT3;
    qsh[n0][oidx] = d0 * dsc;
    qsh[n1][oidx] = d1 * dsc;
    __syncthreads();

    for (int i = t; i < 512; i += 256){
        int nn = i >> 7, tt = i & 127;
        int col = tt >> 3, slot = tt & 7;
        int src;
        if      (slot == 0) src = col;
        else if (slot == 1) src = col + 16;
        else if (slot <  5) src = 32 + 3*col + (slot-2);
        else                src = 32 + 3*(col+16) + (slot-5);
        qdbuf[(size_t)(nb+nn)*128 + tt] = qsh[nn][src];
    }
}

// ---------------------------------------------------------------------------
// CSR build: exclusive scan -> scatter+REORDER into 48-B records.
// ---------------------------------------------------------------------------
__global__ __launch_bounds__(256) void scan_kernel(
    const int* __restrict__ degb, int* __restrict__ rowstart,
    int* __restrict__ cursor)
{
    __shared__ int part[256];
    int t = threadIdx.x;
    int loc[32];
    int s = 0;
    #pragma unroll
    for (int i = 0; i < 32; ++i){ loc[i] = s; s += degb[t*32 + i]; }
    part[t] = s;
    __syncthreads();
    for (int d = 1; d < 256; d <<= 1){
        int v = (t >= d) ? part[t-d] : 0;
        __syncthreads();
        part[t] += v;
        __syncthreads();
    }
    int excl = part[t] - s;
    #pragma unroll
    for (int i = 0; i < 32; ++i){
        int v = excl + loc[i];
        rowstart[t*32 + i] = v;
        cursor[t*32 + i]   = v;
    }
    if (t == 255) rowstart[N_NODES] = excl + s;
}

// 48-B record per edge: [emb16 32B][eattr fp16x4 8B][src 4B][pad 4B].
__global__ __launch_bounds__(256) void scatter_kernel(
    const int* __restrict__ eidx, const float* __restrict__ emb,
    const float* __restrict__ eattr, int* __restrict__ cursor,
    char* __restrict__ recbuf)
{
    int e = blockIdx.x*256 + threadIdx.x;
    int dst = eidx[N_EDGES + e];
    int src = eidx[e];
    float4 a4 = *(const float4*)(eattr + (size_t)e*4);
    const float4* ep = (const float4*)(emb + (size_t)e*16);
    float4 v0 = ep[0], v1 = ep[1], v2 = ep[2], v3 = ep[3];
    half8 h0, h1;
    h0[0]=(_Float16)v0.x; h0[1]=(_Float16)v0.y; h0[2]=(_Float16)v0.z; h0[3]=(_Float16)v0.w;
    h0[4]=(_Float16)v1.x; h0[5]=(_Float16)v1.y; h0[6]=(_Float16)v1.z; h0[7]=(_Float16)v1.w;
    h1[0]=(_Float16)v2.x; h1[1]=(_Float16)v2.y; h1[2]=(_Float16)v2.z; h1[3]=(_Float16)v2.w;
    h1[4]=(_Float16)v3.x; h1[5]=(_Float16)v3.y; h1[6]=(_Float16)v3.z; h1[7]=(_Float16)v3.w;
    half4v y4;
    y4[0]=(_Float16)a4.x; y4[1]=(_Float16)a4.y; y4[2]=(_Float16)a4.z; y4[3]=(_Float16)a4.w;
    int2 yb = *(int2*)&y4;
    int4 tail; tail.x = yb.x; tail.y = yb.y; tail.z = src; tail.w = 0;
    int p = atomicAdd(&cursor[dst], 1);
    char* wp = recbuf + (size_t)p*48;
    *(half8*)(wp)      = h0;
    *(half8*)(wp + 16) = h1;
    *(int4*)(wp + 32)  = tail;
}

// ---------------------------------------------------------------------------
// FUSED edge pass — R14 = R11 VERBATIM (best verified: 235.6 us total,
// edge 94.0 us, absmax 0.0156). R12/R13's bundled micro-opts (8 nodes/block
// + sspf rewrite) regressed to 112 us (warp-pairing doubles degree-variance
// exposure; halved grid kills backfill) -> reverted.
// Structure: 4 nodes/block; GEMM1 true-K16 mfma_f32_16x16x16f16 (fW1 half4,
// 4 KB); GEMM2 fW2 in LDS (32 KB); lin B-fragments in REGISTERS (per-lane
// constants, +32 VGPR); stag 17.4 KB. LDS 54272 B. VGPR 124, no spill.
// 16x16x16 layouts (std CDNA 4-elem k-groups): A[m=lane&15][k=quad*4+j];
// B[k=quad*4+j][n=lane&15]; C col=lane&15, row=quad*4+r.
// 16x16x32 layouts (measured m89/m120) for GEMM2/lin.
// ---------------------------------------------------------------------------

#define G1STAGE(FRAG, OFF) { \
    floatx4 hh = MF16A(ea, FRAG, zzero); \
    stag[g][quad*4+0][(OFF)+col] = (_Float16)sspf(hh[0]); \
    stag[g][quad*4+1][(OFF)+col] = (_Float16)sspf(hh[1]); \
    stag[g][quad*4+2][(OFF)+col] = (_Float16)sspf(hh[2]); \
    stag[g][quad*4+3][(OFF)+col] = (_Float16)sspf(hh[3]); }

#define G2STAGE(A0, A1, B0, B1, OFF) { \
    floatx4 wcx = MF16(A0, B0, zzero); wcx = MF16(A1, B1, wcx); \
    stag[g][quad*4+0][(OFF)+col] = (_Float16)wcx[0]; \
    stag[g][quad*4+1][(OFF)+col] = (_Float16)wcx[1]; \
    stag[g][quad*4+2][(OFF)+col] = (_Float16)wcx[2]; \
    stag[g][quad*4+3][(OFF)+col] = (_Float16)wcx[3]; }

__global__ __launch_bounds__(256, 2) void edge_fused(
    const _Float16* __restrict__ feats16, const char* __restrict__ recbuf,
    const float* __restrict__ Wk1,  const float* __restrict__ Wk2,
    const float* __restrict__ Wlk0, const float* __restrict__ Wlk1,
    const float* __restrict__ Wv1,  const float* __restrict__ Wv2,
    const float* __restrict__ Wlv0, const float* __restrict__ Wlv1,
    const float* __restrict__ qdbuf,
    const int* __restrict__ rowstart,
    float* __restrict__ out)
{
    __shared__ half4v fW1[2][4][64];       // K=16 fragments (4 KB)
    __shared__ half8  fW2[2][16][64];      // 32 KB
    __shared__ _Float16 stag[4][16][136];  // 17.4 KB

    const int t    = threadIdx.x;
    const int lane = t & 63;
    const int col  = lane & 15;
    const int quad = lane >> 4;
    const int g    = t >> 6;          // warp id 0..3

    // ---- lin B-fragments in REGISTERS (per-lane constants, all warps) ----
    half8 rL0k[4], rL1k[4], rL0v[4], rL1v[4];
    #pragma unroll
    for (int ff = 0; ff < 4; ++ff){
        int tile = ff >> 1, s = ff & 1;
        #pragma unroll
        for (int j = 0; j < 8; ++j){
            int k = (s*32 + quad*8 + j)*32 + tile*16 + col;
            rL0k[ff][j] = (_Float16)(Wlk0[k] * 0.125f);
            rL1k[ff][j] = (_Float16)(Wlk1[k] * 0.125f);
            rL0v[ff][j] = (_Float16)(Wlv0[k] * 0.125f);
            rL1v[ff][j] = (_Float16)(Wlv1[k] * 0.125f);
        }
    }

    // ---- preload GEMM1 (K16) + GEMM2 weight fragments (scales folded) ----
    #pragma unroll
    for (int kv = 0; kv < 2; ++kv){
        const float* __restrict__ W1 = kv ? Wv1  : Wk1;
        const float* __restrict__ W2 = kv ? Wv2  : Wk2;
        {
            half4v f;
            #pragma unroll
            for (int j = 0; j < 4; ++j)
                f[j] = (_Float16)(W1[(quad*4 + j)*64 + g*16 + col] * 0.25f);
            fW1[kv][g][lane] = f;
        }
        #pragma unroll
        for (int ff = 0; ff < 4; ++ff){
            int fr = g*4 + ff, tile = fr >> 1, s = fr & 1;
            // fr>=12 produce w3 (cols 96..127): fold INV_SQRT3 here
            float w2sc = (fr >= 12) ? (0.125f * INV_SQRT3) : 0.125f;
            half8 f;
            #pragma unroll
            for (int j = 0; j < 8; ++j)
                f[j] = (_Float16)(W2[(s*32 + quad*8 + j)*128 + tile*16 + col] * w2sc);
            fW2[kv][fr][lane] = f;
        }
    }
    __syncthreads();     // the only block-wide barrier

    const floatx4 zzero = {0.f, 0.f, 0.f, 0.f};

    const int n  = blockIdx.x*4 + g;
    const int r0 = rowstart[n];
    const int dcount = rowstart[n+1] - r0;

    const float* qdp = qdbuf + (size_t)n*128 + col*8;
    float4 qa = *(const float4*)qdp;
    float4 qb = *(const float4*)(qdp + 4);

    float macc0=0.f, macc1=0.f, macc2=0.f, macc3=0.f;
    float macc4=0.f, macc5=0.f, macc6=0.f, macc7=0.f;
    float zacc = 0.f;

    for (int tb = 0; tb < dcount; tb += 16){
        int slot = tb + col;
        int pc = r0 + ((slot < dcount) ? slot : (dcount-1));

        // ---- per-edge 48-B record (CSR-sequential across lanes) ----
        const char* rp = recbuf + (size_t)pc*48;
        half4v ea = *(const half4v*)(rp + quad*8);   // A[m][k=quad*4+j], all quads
        half4v yh = *(const half4v*)(rp + 32);
        const int srcm = *(const int*)(rp + 40);
        const _Float16* fsrc = feats16 + (size_t)srcm*128;

        // de-interleaved x planes: direct half8 loads
        half8 hx  = *(const half8*)(fsrc + quad*8);
        half8 hxa = *(const half8*)(fsrc + 32 + quad*8);
        half8 hxb = *(const half8*)(fsrc + 64 + quad*8);
        half8 hxc = *(const half8*)(fsrc + 96 + quad*8);

        // ---- shared x*y products, PACKED fp16 (used by BOTH k and v) ----
        _Float16 hy0  = yh[0];
        _Float16 hy1a = yh[1];
        _Float16 hy1b = yh[2];
        _Float16 hy1c = yh[3];
        half8 y0v  = {hy0,hy0,hy0,hy0,hy0,hy0,hy0,hy0};
        half8 y1av = {hy1a,hy1a,hy1a,hy1a,hy1a,hy1a,hy1a,hy1a};
        half8 y1bv = {hy1b,hy1b,hy1b,hy1b,hy1b,hy1b,hy1b,hy1b};
        half8 y1cv = {hy1c,hy1c,hy1c,hy1c,hy1c,hy1c,hy1c,hy1c};
        half8 px00 = hx  * y0v;
        half8 pxa  = hx  * y1av;
        half8 pxb  = hx  * y1bv;
        half8 pxc  = hx  * y1cv;
        half8 pay  = hxa * y0v;
        half8 pby  = hxb * y0v;
        half8 pcy  = hxc * y0v;
        half8 pdot = hxa*y1av + hxb*y1bv + hxc*y1cv;   // *INV_SQRT3 folded in fW2

        // ---- GEMM1 (k AND v, shared A, K=16) -> ssp -> staged ----
        G1STAGE(fW1[0][0][lane],   0)
        G1STAGE(fW1[0][1][lane],  16)
        G1STAGE(fW1[0][2][lane],  32)
        G1STAGE(fW1[0][3][lane],  48)
        G1STAGE(fW1[1][0][lane],  64)
        G1STAGE(fW1[1][1][lane],  80)
        G1STAGE(fW1[1][2][lane],  96)
        G1STAGE(fW1[1][3][lane], 112)

        half8 a0k = *(const half8*)&stag[g][col][     quad*8];
        half8 a1k = *(const half8*)&stag[g][col][32 + quad*8];
        half8 a0v = *(const half8*)&stag[g][col][64 + quad*8];
        half8 a1v = *(const half8*)&stag[g][col][96 + quad*8];

        // ---- GEMM2 k: staged immediately (overlay; same-wave DS in-order) -
        G2STAGE(a0k, a1k, fW2[0][ 0][lane], fW2[0][ 1][lane],   0)
        G2STAGE(a0k, a1k, fW2[0][ 2][lane], fW2[0][ 3][lane],  16)
        G2STAGE(a0k, a1k, fW2[0][ 4][lane], fW2[0][ 5][lane],  32)
        G2STAGE(a0k, a1k, fW2[0][ 6][lane], fW2[0][ 7][lane],  48)
        G2STAGE(a0k, a1k, fW2[0][ 8][lane], fW2[0][ 9][lane],  64)
        G2STAGE(a0k, a1k, fW2[0][10][lane], fW2[0][11][lane],  80)
        G2STAGE(a0k, a1k, fW2[0][12][lane], fW2[0][13][lane],  96)
        G2STAGE(a0k, a1k, fW2[0][14][lane], fW2[0][15][lane], 112)

        half8 w0hk = *(const half8*)&stag[g][col][     quad*8];
        half8 w1hk = *(const half8*)&stag[g][col][32 + quad*8];
        half8 w2hk = *(const half8*)&stag[g][col][64 + quad*8];
        half8 w3hk = *(const half8*)&stag[g][col][96 + quad*8];

        // ---- GEMM2 v (k-reads above issue before these overlay writes) ----
        G2STAGE(a0v, a1v, fW2[1][ 0][lane], fW2[1][ 1][lane],   0)
        G2STAGE(a0v, a1v, fW2[1][ 2][lane], fW2[1][ 3][lane],  16)
        G2STAGE(a0v, a1v, fW2[1][ 4][lane], fW2[1][ 5][lane],  32)
        G2STAGE(a0v, a1v, fW2[1][ 6][lane], fW2[1][ 7][lane],  48)
        G2STAGE(a0v, a1v, fW2[1][ 8][lane], fW2[1][ 9][lane],  64)
        G2STAGE(a0v, a1v, fW2[1][10][lane], fW2[1][11][lane],  80)
        G2STAGE(a0v, a1v, fW2[1][12][lane], fW2[1][13][lane],  96)
        G2STAGE(a0v, a1v, fW2[1][14][lane], fW2[1][15][lane], 112)

        // ---- uvu k fragments: ONE packed mul each ----
        half8 fk0s0 = w0hk * px00;
        half8 fk0s1 = w3hk * pdot;
        half8 fc0s0 = w1hk * pxa;
        half8 fc1s0 = w1hk * pxb;
        half8 fc2s0 = w1hk * pxc;
        half8 fc0s1 = w2hk * pay;
        half8 fc1s1 = w2hk * pby;
        half8 fc2s1 = w2hk * pcy;

        // ---- lin k folded into ddv as produced (B from registers) ----
        floatx4 ddv = zzero;
        {
            floatx4 tk;
            tk = MF16(fk0s0, rL0k[0], zzero); tk = MF16(fk0s1, rL0k[1], tk);
            ddv += tk * qa.x;
            tk = MF16(fk0s0, rL0k[2], zzero); tk = MF16(fk0s1, rL0k[3], tk);
            ddv += tk * qa.y;
            tk = MF16(fc0s0, rL1k[0], zzero); tk = MF16(fc0s1, rL1k[1], tk);
            ddv += tk * qa.z;
            tk = MF16(fc1s0, rL1k[0], zzero); tk = MF16(fc1s1, rL1k[1], tk);
            ddv += tk * qa.w;
            tk = MF16(fc2s0, rL1k[0], zzero); tk = MF16(fc2s1, rL1k[1], tk);
            ddv += tk * qb.x;
            tk = MF16(fc0s0, rL1k[2], zzero); tk = MF16(fc0s1, rL1k[3], tk);
            ddv += tk * qb.y;
            tk = MF16(fc1s0, rL1k[2], zzero); tk = MF16(fc1s1, rL1k[3], tk);
            ddv += tk * qb.z;
            tk = MF16(fc2s0, rL1k[2], zzero); tk = MF16(fc2s1, rL1k[3], tk);
            ddv += tk * qb.w;
        }

        float cf0, cf1, cf2, cf3;
        #pragma unroll
        for (int r = 0; r < 4; ++r){
            float dd = ddv[r];
            dd += __shfl_xor(dd, 1);
            dd += __shfl_xor(dd, 2);
            dd += __shfl_xor(dd, 4);
            dd += __shfl_xor(dd, 8);
            // cutoff const: diff = pos[src]-pos[src] == 0 (reference bug)
            bool valid = (tb + quad*4 + r) < dcount;
            float ev = valid ? (0.9048374180359595f * __expf(dd)) : 0.f;
            zacc += ev;
            float cf = sqrtf(ev);
            if (r==0) cf0 = cf; else if (r==1) cf1 = cf;
            else if (r==2) cf2 = cf; else cf3 = cf;
        }

        // ---- read back w_v, packed v fragments (reuse same registers) ----
        {
            half8 w0hv = *(const half8*)&stag[g][col][     quad*8];
            half8 w1hv = *(const half8*)&stag[g][col][32 + quad*8];
            half8 w2hv = *(const half8*)&stag[g][col][64 + quad*8];
            half8 w3hv = *(const half8*)&stag[g][col][96 + quad*8];
            fk0s0 = w0hv * px00;
            fk0s1 = w3hv * pdot;
            fc0s0 = w1hv * pxa;
            fc1s0 = w1hv * pxb;
            fc2s0 = w1hv * pxc;
            fc0s1 = w2hv * pay;
            fc1s1 = w2hv * pby;
            fc2s1 = w2hv * pcy;
        }

        // ---- lin v folded straight into macc scalars (B from registers) --
        {
            floatx4 tv;
            tv = MF16(fk0s0, rL0v[0], zzero); tv = MF16(fk0s1, rL0v[1], tv);
            macc0 += cf0*tv[0] + cf1*tv[1] + cf2*tv[2] + cf3*tv[3];
            tv = MF16(fk0s0, rL0v[2], zzero); tv = MF16(fk0s1, rL0v[3], tv);
            macc1 += cf0*tv[0] + cf1*tv[1] + cf2*tv[2] + cf3*tv[3];
            tv = MF16(fc0s0, rL1v[0], zzero); tv = MF16(fc0s1, rL1v[1], tv);
            macc2 += cf0*tv[0] + cf1*tv[1] + cf2*tv[2] + cf3*tv[3];
            tv = MF16(fc1s0, rL1v[0], zzero); tv = MF16(fc1s1, rL1v[1], tv);
            macc3 += cf0*tv[0] + cf1*tv[1] + cf2*tv[2] + cf3*tv[3];
            tv = MF16(fc2s0, rL1v[0], zzero); tv = MF16(fc2s1, rL1v[1], tv);
            macc4 += cf0*tv[0] + cf1*tv[1] + cf2*tv[2] + cf3*tv[3];
            tv = MF16(fc0s0, rL1v[2], zzero); tv = MF16(fc0s1, rL1v[3], tv);
            macc5 += cf0*tv[0] + cf1*tv[1] + cf2*tv[2] + cf3*tv[3];
            tv = MF16(fc1s0, rL1v[2], zzero); tv = MF16(fc1s1, rL1v[3], tv);
            macc6 += cf0*tv[0] + cf1*tv[1] + cf2*tv[2] + cf3*tv[3];
            tv = MF16(fc2s0, rL1v[2], zzero); tv = MF16(fc2s1, rL1v[3], tv);
            macc7 += cf0*tv[0] + cf1*tv[1] + cf2*tv[2] + cf3*tv[3];
        }
    }

    // ---- reduce over quads; rsqrt(z) factored scaling; write out ----
    macc0 += __shfl_xor(macc0, 16); macc0 += __shfl_xor(macc0, 32);
    macc1 += __shfl_xor(macc1, 16); macc1 += __shfl_xor(macc1, 32);
    macc2 += __shfl_xor(macc2, 16); macc2 += __shfl_xor(macc2, 32);
    macc3 += __shfl_xor(macc3, 16); macc3 += __shfl_xor(macc3, 32);
    macc4 += __shfl_xor(macc4, 16); macc4 += __shfl_xor(macc4, 32);
    macc5 += __shfl_xor(macc5, 16); macc5 += __shfl_xor(macc5, 32);
    macc6 += __shfl_xor(macc6, 16); macc6 += __shfl_xor(macc6, 32);
    macc7 += __shfl_xor(macc7, 16); macc7 += __shfl_xor(macc7, 32);
    zacc  += __shfl_xor(zacc, 16);  zacc  += __shfl_xor(zacc, 32);
    float rz = (zacc > 0.f) ? rsqrtf(zacc) : 0.f;

    if (lane < 16){
        float* op = out + (size_t)n*128;
        op[col]                 += macc0 * rz;
        op[col + 16]            += macc1 * rz;
        op[32 + 3*col + 0]      += macc2 * rz;
        op[32 + 3*col + 1]      += macc3 * rz;
        op[32 + 3*col + 2]      += macc4 * rz;
        op[32 + 3*(col+16) + 0] += macc5 * rz;
        op[32 + 3*(col+16) + 1] += macc6 * rz;
        op[32 + 3*(col+16) + 2] += macc7 * rz;
    }
}

extern "C" void kernel_launch(void* const* d_in, const int* in_sizes, int n_in,
                              void* d_out, int out_size, void* d_ws, size_t ws_size,
                              hipStream_t stream)
{
    const float* feats = (const float*)d_in[0];
    const float* attrs = (const float*)d_in[1];
    const float* emb   = (const float*)d_in[2];
    const float* eattr = (const float*)d_in[3];
    // d_in[4] positions: unused (reference computes positions[src]-positions[src] == 0)
    const float* Wq0  = (const float*)d_in[5];
    const float* Wq1  = (const float*)d_in[6];
    const float* Wk1  = (const float*)d_in[7];
    const float* Wk2  = (const float*)d_in[8];
    const float* Wv1  = (const float*)d_in[9];
    const float* Wv2  = (const float*)d_in[10];
    const float* Wlk0 = (const float*)d_in[11];
    const float* Wlk1 = (const float*)d_in[12];
    const float* Wlv0 = (const float*)d_in[13];
    const float* Wlv1 = (const float*)d_in[14];
    const float* Wd0  = (const float*)d_in[15];
    const float* Wd1  = (const float*)d_in[16];
    const float* Ws0  = (const float*)d_in[17];
    const float* Ws1  = (const float*)d_in[18];
    const int*   eidx = (const int*)d_in[19];

    float* out   = (float*)d_out;
    // workspace (18.97 MB total, < 20.02 MB proven-passing R1 footprint):
    char* recbuf = (char*)d_ws;                               // E*48 B = 12.58MB
    float* qdbuf = (float*)(recbuf + (size_t)N_EDGES*48);     // N*128 f = 4.19MB
    _Float16* feats16 = (_Float16*)(qdbuf + (size_t)N_NODES*128); // N*128 h = 2.1MB
    int*   degb  = (int*)(feats16 + (size_t)N_NODES*128);     // N
    int*   rowst = degb + N_NODES;                            // N+1
    int*   curs  = rowst + N_NODES + 1;                       // N

    hipMemsetAsync(degb, 0, N_NODES*sizeof(int), stream);
    node_kernel<<<N_NODES/4, 256, 0, stream>>>(feats, attrs, Wq0, Wq1, Wd0, Wd1,
                                               Ws0, Ws1, qdbuf, out, feats16,
                                               eidx, degb);
    scan_kernel<<<1, 256, 0, stream>>>(degb, rowst, curs);
    scatter_kernel<<<N_EDGES/256, 256, 0, stream>>>(eidx, emb, eattr, curs,
                                                    recbuf);
    edge_fused<<<N_NODES/4, 256, 0, stream>>>(feats16, recbuf,
                                              Wk1, Wk2, Wlk0, Wlk1,
                                              Wv1, Wv2, Wlv0, Wlv1,
                                              qdbuf, rowst, out);
}